// Round 1
// baseline (1079.832 us; speedup 1.0000x reference)
//
#include <hip/hip_runtime.h>
#include <stdint.h>
#include <math.h>

#define TTOK 8192
#define DDIM 1024
#define FDIM 4096
#define NEXP 8
#define NASG (TTOK*2)

typedef __attribute__((ext_vector_type(8))) short bf16x8;
typedef __attribute__((ext_vector_type(4))) float f32x4;
typedef __attribute__((ext_vector_type(4))) float f4v;
typedef __attribute__((ext_vector_type(8))) unsigned short u16x8;

__device__ __forceinline__ unsigned short f2bf(float f) {
  union { float f; unsigned int u; } v; v.f = f;
  unsigned int u = v.u;
  u += 0x7fffu + ((u >> 16) & 1u);   // round-to-nearest-even
  return (unsigned short)(u >> 16);
}

__device__ __forceinline__ void gload16(const void* g, void* l) {
  __builtin_amdgcn_global_load_lds(
    (__attribute__((address_space(1))) unsigned int*)(uintptr_t)g,
    (__attribute__((address_space(3))) unsigned int*)(uintptr_t)l,
    16, 0, 0);
}

// ---------------- router: one wave per token, fp64 accumulate ----------------
__global__ __launch_bounds__(256) void router_kernel(
    const float* __restrict__ x, const float* __restrict__ rw,
    const float* __restrict__ rb, int* __restrict__ topi,
    float* __restrict__ topw, int* __restrict__ counts)
{
  int wave = threadIdx.x >> 6;
  int lane = threadIdx.x & 63;
  int t = blockIdx.x * 4 + wave;
  if (t >= TTOK) return;
  double acc[8];
#pragma unroll
  for (int e = 0; e < 8; e++) acc[e] = 0.0;
  const float* xr = x + (size_t)t * DDIM;
  for (int d = lane; d < DDIM; d += 64) {
    double xv = (double)xr[d];
    const float* rwr = rw + (size_t)d * 8;
#pragma unroll
    for (int e = 0; e < 8; e++) acc[e] += xv * (double)rwr[e];
  }
#pragma unroll
  for (int e = 0; e < 8; e++) {
    for (int off = 32; off >= 1; off >>= 1)
      acc[e] += __shfl_xor(acc[e], off);
  }
  if (lane == 0) {
    float lg[8];
#pragma unroll
    for (int e = 0; e < 8; e++) lg[e] = (float)acc[e] + rb[e];
    int i0 = 0;
    for (int e = 1; e < 8; e++) if (lg[e] > lg[i0]) i0 = e;   // ties -> lowest idx
    int i1 = -1;
    for (int e = 0; e < 8; e++) {
      if (e == i0) continue;
      if (i1 < 0 || lg[e] > lg[i1]) i1 = e;
    }
    double z = exp((double)lg[i1] - (double)lg[i0]);
    float w0 = (float)(1.0 / (1.0 + z));
    topi[t*2]   = i0;  topi[t*2+1] = i1;
    topw[t*2]   = w0;  topw[t*2+1] = 1.0f - w0;
    atomicAdd(&counts[i0], 1);
    atomicAdd(&counts[i1], 1);
  }
}

__global__ void scan_kernel(const int* __restrict__ counts, int* __restrict__ offsets) {
  if (threadIdx.x == 0) {
    int s = 0;
    for (int e = 0; e < 8; e++) { offsets[e] = s; s += counts[e]; }
    offsets[8] = s;
  }
}

// ------------- deterministic stable counting sort of assignments -------------
__global__ __launch_bounds__(256) void permbuild_kernel(
    const int* __restrict__ topi, const float* __restrict__ topw,
    const int* __restrict__ offsets, int* __restrict__ perm, float* __restrict__ pw)
{
  __shared__ int hist[256 * 8];
  int tid = threadIdx.x;
  int cnt[8];
#pragma unroll
  for (int e = 0; e < 8; e++) cnt[e] = 0;
  int base = tid * 64;
  for (int i = 0; i < 64; i++) cnt[topi[base + i]]++;
#pragma unroll
  for (int e = 0; e < 8; e++) hist[tid*8 + e] = cnt[e];
  __syncthreads();
  if (tid < 8) {
    int s = 0;
    for (int th = 0; th < 256; th++) { int v = hist[th*8 + tid]; hist[th*8 + tid] = s; s += v; }
  }
  __syncthreads();
  int pos[8];
#pragma unroll
  for (int e = 0; e < 8; e++) pos[e] = offsets[e] + hist[tid*8 + e];
  for (int i = 0; i < 64; i++) {
    int a = base + i;
    int e = topi[a];
    int p = pos[e]++;
    perm[p] = a >> 1;
    pw[p] = topw[a];
  }
}

// ---------------- x fp32 -> bf16 ----------------
__global__ __launch_bounds__(256) void cvt_x_kernel(
    const float* __restrict__ x, unsigned short* __restrict__ xb)
{
  size_t i = ((size_t)blockIdx.x * 256 + threadIdx.x) * 8;
  if (i >= (size_t)TTOK * DDIM) return;
  f4v v0 = *(const f4v*)(x + i);
  f4v v1 = *(const f4v*)(x + i + 4);
  u16x8 o;
  o[0]=f2bf(v0[0]); o[1]=f2bf(v0[1]); o[2]=f2bf(v0[2]); o[3]=f2bf(v0[3]);
  o[4]=f2bf(v1[0]); o[5]=f2bf(v1[1]); o[6]=f2bf(v1[2]); o[7]=f2bf(v1[3]);
  *(u16x8*)(xb + i) = o;
}

// ------- batched transpose + convert: [E][R][C] f32 -> [E][C][R] bf16 --------
__global__ __launch_bounds__(256) void transpose_kernel(
    const float* __restrict__ w, unsigned short* __restrict__ wt, int R, int C)
{
  __shared__ float tile[64][65];
  int tilesPerRow = C >> 6;
  int tilesPerMat = (R >> 6) * tilesPerRow;
  int b = blockIdx.x;
  int e = b / tilesPerMat;
  int rem = b - e * tilesPerMat;
  int tr = rem / tilesPerRow;
  int tc = rem - tr * tilesPerRow;
  int tid = threadIdx.x;
  size_t ibase = (size_t)e*R*C + ((size_t)tr*64)*C + (size_t)tc*64;
#pragma unroll
  for (int i = 0; i < 16; i++) {
    int idx = tid + i*256;
    int r = idx >> 6, c = idx & 63;
    tile[r][c] = w[ibase + (size_t)r*C + c];
  }
  __syncthreads();
  size_t obase = (size_t)e*R*C + ((size_t)tc*64)*R + (size_t)tr*64;
#pragma unroll
  for (int i = 0; i < 16; i++) {
    int idx = tid + i*256;
    int r = idx >> 6, c = idx & 63;
    wt[obase + (size_t)r*R + c] = f2bf(tile[c][r]);
  }
}

// ---------------- grouped GEMM1: H = gelu(X_gather @ w1 + b1) ----------------
// A: xb gathered rows [128 x 64] bf16; B: w1t[e] ([F][D], K-contig) [128 x 64]
__global__ __launch_bounds__(256) void gemm1_kernel(
    const unsigned short* __restrict__ xb,
    const unsigned short* __restrict__ w1t,
    const float* __restrict__ b1,
    const int* __restrict__ perm,
    const int* __restrict__ offsets,
    unsigned short* __restrict__ H)
{
  const int NT = FDIM/128;       // 32
  const int MAXRT = TTOK/128;    // 64
  int b = blockIdx.x;
  int e = b / (MAXRT*NT);
  int rem = b - e*(MAXRT*NT);
  int rt = rem / NT;
  int nt = rem - rt*NT;
  int off = offsets[e];
  int n_e = offsets[e+1] - off;
  if (rt*128 >= n_e) return;

  __shared__ __align__(16) unsigned short Alds[128*64];
  __shared__ __align__(16) unsigned short Blds[128*64];
  int tid = threadIdx.x;

  const char* ab[4];
  const char* bb[4];
#pragma unroll
  for (int i = 0; i < 4; i++) {
    int slot = tid + i*256;
    int row = slot >> 3;
    int cb = (slot & 7) * 16;
    int sg = off + rt*128 + row; if (sg > NASG-1) sg = NASG-1;
    int tok = perm[sg];
    ab[i] = (const char*)xb + ((size_t)tok*DDIM)*2 + cb;
    bb[i] = (const char*)w1t + ((size_t)e*FDIM + (size_t)nt*128 + row)*DDIM*2 + cb;
  }

  f32x4 acc[4][4];
#pragma unroll
  for (int m = 0; m < 4; m++)
#pragma unroll
    for (int n = 0; n < 4; n++) acc[m][n] = (f32x4){0.f,0.f,0.f,0.f};

  int lane = tid & 63;
  int wave = tid >> 6;
  int wr = wave >> 1, wc = wave & 1;
  int aoff = ((wr*64 + (lane & 15))*64 + (lane >> 4)*8) * 2;   // bytes
  int boff = ((wc*64 + (lane & 15))*64 + (lane >> 4)*8) * 2;

  for (int kk = 0; kk < DDIM/64; kk++) {
    __syncthreads();
#pragma unroll
    for (int i = 0; i < 4; i++) {
      gload16(ab[i] + (size_t)kk*128, (char*)Alds + (size_t)(tid + i*256)*16);
      gload16(bb[i] + (size_t)kk*128, (char*)Blds + (size_t)(tid + i*256)*16);
    }
    __syncthreads();
#pragma unroll
    for (int ks = 0; ks < 2; ks++) {
      bf16x8 af[4], bfr[4];
#pragma unroll
      for (int m = 0; m < 4; m++)
        af[m] = *(const bf16x8*)((const char*)Alds + aoff + m*(16*128) + ks*64);
#pragma unroll
      for (int n = 0; n < 4; n++)
        bfr[n] = *(const bf16x8*)((const char*)Blds + boff + n*(16*128) + ks*64);
#pragma unroll
      for (int m = 0; m < 4; m++)
#pragma unroll
        for (int n = 0; n < 4; n++)
          acc[m][n] = __builtin_amdgcn_mfma_f32_16x16x32_bf16(af[m], bfr[n], acc[m][n], 0, 0, 0);
    }
  }

  int rowb = rt*128 + wr*64 + (lane >> 4)*4;
  int colb = nt*128 + wc*64 + (lane & 15);
#pragma unroll
  for (int m = 0; m < 4; m++) {
#pragma unroll
    for (int j = 0; j < 4; j++) {
      int sl = rowb + m*16 + j;
      if (sl < n_e) {
        size_t hrow = (size_t)(off + sl) * FDIM;
#pragma unroll
        for (int n = 0; n < 4; n++) {
          int col = colb + n*16;
          float v = acc[m][n][j] + b1[e*FDIM + col];
          float g = 0.5f * v * (1.0f + erff(v * 0.70710678118654752f));
          H[hrow + col] = f2bf(g);
        }
      }
    }
  }
}

// -------- grouped GEMM2: out[tok] += cw * (H @ w2 + b2), atomic scatter ------
__global__ __launch_bounds__(256) void gemm2_kernel(
    const unsigned short* __restrict__ H,
    const unsigned short* __restrict__ w2t,   // [E][D][F], K-contig
    const float* __restrict__ b2,
    const int* __restrict__ perm,
    const float* __restrict__ pw,
    const int* __restrict__ offsets,
    float* __restrict__ out)
{
  const int NT = DDIM/128;       // 8
  const int MAXRT = TTOK/128;    // 64
  int b = blockIdx.x;
  int e = b / (MAXRT*NT);
  int rem = b - e*(MAXRT*NT);
  int rt = rem / NT;
  int nt = rem - rt*NT;
  int off = offsets[e];
  int n_e = offsets[e+1] - off;
  if (rt*128 >= n_e) return;

  __shared__ __align__(16) unsigned short Alds[128*64];
  __shared__ __align__(16) unsigned short Blds[128*64];
  int tid = threadIdx.x;

  const char* ab[4];
  const char* bb[4];
#pragma unroll
  for (int i = 0; i < 4; i++) {
    int slot = tid + i*256;
    int row = slot >> 3;
    int cb = (slot & 7) * 16;
    int sg = off + rt*128 + row; if (sg > NASG-1) sg = NASG-1;
    ab[i] = (const char*)H + ((size_t)sg*FDIM)*2 + cb;
    bb[i] = (const char*)w2t + ((size_t)e*DDIM + (size_t)nt*128 + row)*FDIM*2 + cb;
  }

  f32x4 acc[4][4];
#pragma unroll
  for (int m = 0; m < 4; m++)
#pragma unroll
    for (int n = 0; n < 4; n++) acc[m][n] = (f32x4){0.f,0.f,0.f,0.f};

  int lane = tid & 63;
  int wave = tid >> 6;
  int wr = wave >> 1, wc = wave & 1;
  int aoff = ((wr*64 + (lane & 15))*64 + (lane >> 4)*8) * 2;
  int boff = ((wc*64 + (lane & 15))*64 + (lane >> 4)*8) * 2;

  for (int kk = 0; kk < FDIM/64; kk++) {
    __syncthreads();
#pragma unroll
    for (int i = 0; i < 4; i++) {
      gload16(ab[i] + (size_t)kk*128, (char*)Alds + (size_t)(tid + i*256)*16);
      gload16(bb[i] + (size_t)kk*128, (char*)Blds + (size_t)(tid + i*256)*16);
    }
    __syncthreads();
#pragma unroll
    for (int ks = 0; ks < 2; ks++) {
      bf16x8 af[4], bfr[4];
#pragma unroll
      for (int m = 0; m < 4; m++)
        af[m] = *(const bf16x8*)((const char*)Alds + aoff + m*(16*128) + ks*64);
#pragma unroll
      for (int n = 0; n < 4; n++)
        bfr[n] = *(const bf16x8*)((const char*)Blds + boff + n*(16*128) + ks*64);
#pragma unroll
      for (int m = 0; m < 4; m++)
#pragma unroll
        for (int n = 0; n < 4; n++)
          acc[m][n] = __builtin_amdgcn_mfma_f32_16x16x32_bf16(af[m], bfr[n], acc[m][n], 0, 0, 0);
    }
  }

  int rowb = rt*128 + wr*64 + (lane >> 4)*4;
  int colb = nt*128 + wc*64 + (lane & 15);
#pragma unroll
  for (int m = 0; m < 4; m++) {
#pragma unroll
    for (int j = 0; j < 4; j++) {
      int sl = rowb + m*16 + j;
      if (sl < n_e) {
        int slot = off + sl;
        int tok = perm[slot];
        float w = pw[slot];
        float* orow = out + (size_t)tok * DDIM;
#pragma unroll
        for (int n = 0; n < 4; n++) {
          int col = colb + n*16;
          float y = acc[m][n][j] + b2[e*DDIM + col];
          atomicAdd(orow + col, w * y);
        }
      }
    }
  }
}

extern "C" void kernel_launch(void* const* d_in, const int* in_sizes, int n_in,
                              void* d_out, int out_size, void* d_ws, size_t ws_size,
                              hipStream_t stream) {
  const float* x  = (const float*)d_in[0];
  const float* w1 = (const float*)d_in[1];
  const float* b1 = (const float*)d_in[2];
  const float* w2 = (const float*)d_in[3];
  const float* b2 = (const float*)d_in[4];
  const float* rw = (const float*)d_in[5];
  const float* rb = (const float*)d_in[6];
  float* out = (float*)d_out;

  char* p = (char*)d_ws;
  size_t o = 0;
  auto take = [&](size_t bytes) -> void* {
    void* r = p + o;
    o = (o + bytes + 255) & ~(size_t)255;
    return r;
  };
  int*            counts  = (int*)take(NEXP * 4);
  int*            offsets = (int*)take((NEXP + 1) * 4);
  int*            topi    = (int*)take((size_t)NASG * 4);
  float*          topw    = (float*)take((size_t)NASG * 4);
  int*            perm    = (int*)take((size_t)NASG * 4);
  float*          pw      = (float*)take((size_t)NASG * 4);
  unsigned short* xb      = (unsigned short*)take((size_t)TTOK * DDIM * 2);
  unsigned short* w1t     = (unsigned short*)take((size_t)NEXP * FDIM * DDIM * 2);
  unsigned short* w2t     = (unsigned short*)take((size_t)NEXP * DDIM * FDIM * 2);
  unsigned short* H       = (unsigned short*)take((size_t)NASG * FDIM * 2);

  if (o > ws_size) {   // workspace insufficient: fail visibly (zeros)
    hipMemsetAsync(d_out, 0, (size_t)out_size * 4, stream);
    return;
  }

  hipMemsetAsync(counts, 0, NEXP * 4, stream);
  hipMemsetAsync(d_out, 0, (size_t)out_size * 4, stream);

  router_kernel<<<TTOK/4, 256, 0, stream>>>(x, rw, rb, topi, topw, counts);
  scan_kernel<<<1, 64, 0, stream>>>(counts, offsets);
  permbuild_kernel<<<1, 256, 0, stream>>>(topi, topw, offsets, perm, pw);
  cvt_x_kernel<<<(TTOK*DDIM/8)/256, 256, 0, stream>>>(x, xb);
  transpose_kernel<<<NEXP*(DDIM/64)*(FDIM/64), 256, 0, stream>>>(w1, w1t, DDIM, FDIM);
  transpose_kernel<<<NEXP*(FDIM/64)*(DDIM/64), 256, 0, stream>>>(w2, w2t, FDIM, DDIM);
  gemm1_kernel<<<NEXP*(TTOK/128)*(FDIM/128), 256, 0, stream>>>(xb, w1t, b1, perm, offsets, H);
  gemm2_kernel<<<NEXP*(TTOK/128)*(DDIM/128), 256, 0, stream>>>(H, w2t, b2, perm, pw, offsets, out);
}

// Round 2
// 840.633 us; speedup vs baseline: 1.2845x; 1.2845x over previous
//
#include <hip/hip_runtime.h>
#include <stdint.h>
#include <math.h>

#define TTOK 8192
#define DDIM 1024
#define FDIM 4096
#define NEXP 8
#define NASG (TTOK*2)
#define MAXMT 32   // max 256-row tiles per expert (worst case: all tokens on one expert)

typedef __attribute__((ext_vector_type(8))) short bf16x8;
typedef __attribute__((ext_vector_type(4))) float f32x4;
typedef __attribute__((ext_vector_type(4))) float f4v;
typedef __attribute__((ext_vector_type(8))) unsigned short u16x8;

__device__ __forceinline__ unsigned short f2bf(float f) {
  union { float f; unsigned int u; } v; v.f = f;
  unsigned int u = v.u;
  u += 0x7fffu + ((u >> 16) & 1u);   // round-to-nearest-even
  return (unsigned short)(u >> 16);
}

__device__ __forceinline__ void gload16(const void* g, void* l) {
  __builtin_amdgcn_global_load_lds(
    (__attribute__((address_space(1))) unsigned int*)(uintptr_t)g,
    (__attribute__((address_space(3))) unsigned int*)(uintptr_t)l,
    16, 0, 0);
}

// ---------------- router: one wave per token, fp64 accumulate ----------------
__global__ __launch_bounds__(256) void router_kernel(
    const float* __restrict__ x, const float* __restrict__ rw,
    const float* __restrict__ rb, int* __restrict__ topi,
    float* __restrict__ topw, int* __restrict__ counts)
{
  int wave = threadIdx.x >> 6;
  int lane = threadIdx.x & 63;
  int t = blockIdx.x * 4 + wave;
  if (t >= TTOK) return;
  double acc[8];
#pragma unroll
  for (int e = 0; e < 8; e++) acc[e] = 0.0;
  const float* xr = x + (size_t)t * DDIM;
  for (int d = lane; d < DDIM; d += 64) {
    double xv = (double)xr[d];
    const float* rwr = rw + (size_t)d * 8;
#pragma unroll
    for (int e = 0; e < 8; e++) acc[e] += xv * (double)rwr[e];
  }
#pragma unroll
  for (int e = 0; e < 8; e++) {
    for (int off = 32; off >= 1; off >>= 1)
      acc[e] += __shfl_xor(acc[e], off);
  }
  if (lane == 0) {
    float lg[8];
#pragma unroll
    for (int e = 0; e < 8; e++) lg[e] = (float)acc[e] + rb[e];
    int i0 = 0;
    for (int e = 1; e < 8; e++) if (lg[e] > lg[i0]) i0 = e;   // ties -> lowest idx
    int i1 = -1;
    for (int e = 0; e < 8; e++) {
      if (e == i0) continue;
      if (i1 < 0 || lg[e] > lg[i1]) i1 = e;
    }
    double z = exp((double)lg[i1] - (double)lg[i0]);
    float w0 = (float)(1.0 / (1.0 + z));
    topi[t*2]   = i0;  topi[t*2+1] = i1;
    topw[t*2]   = w0;  topw[t*2+1] = 1.0f - w0;
    atomicAdd(&counts[i0], 1);
    atomicAdd(&counts[i1], 1);
  }
}

__global__ void scan_kernel(const int* __restrict__ counts, int* __restrict__ offsets) {
  if (threadIdx.x == 0) {
    int s = 0;
    for (int e = 0; e < 8; e++) { offsets[e] = s; s += counts[e]; }
    offsets[8] = s;
  }
}

// ------------- deterministic stable counting sort of assignments -------------
__global__ __launch_bounds__(256) void permbuild_kernel(
    const int* __restrict__ topi, const int* __restrict__ offsets,
    int* __restrict__ perm, int* __restrict__ islot)
{
  __shared__ int hist[256 * 8];
  int tid = threadIdx.x;
  int cnt[8];
#pragma unroll
  for (int e = 0; e < 8; e++) cnt[e] = 0;
  int base = tid * 64;
  for (int i = 0; i < 64; i++) cnt[topi[base + i]]++;
#pragma unroll
  for (int e = 0; e < 8; e++) hist[tid*8 + e] = cnt[e];
  __syncthreads();
  if (tid < 8) {
    int s = 0;
    for (int th = 0; th < 256; th++) { int v = hist[th*8 + tid]; hist[th*8 + tid] = s; s += v; }
  }
  __syncthreads();
  int pos[8];
#pragma unroll
  for (int e = 0; e < 8; e++) pos[e] = offsets[e] + hist[tid*8 + e];
  for (int i = 0; i < 64; i++) {
    int a = base + i;
    int e = topi[a];
    int p = pos[e]++;
    perm[p] = a >> 1;
    islot[a] = p;
  }
}

// ---------------- x fp32 -> bf16 ----------------
__global__ __launch_bounds__(256) void cvt_x_kernel(
    const float* __restrict__ x, unsigned short* __restrict__ xb)
{
  size_t i = ((size_t)blockIdx.x * 256 + threadIdx.x) * 8;
  if (i >= (size_t)TTOK * DDIM) return;
  f4v v0 = *(const f4v*)(x + i);
  f4v v1 = *(const f4v*)(x + i + 4);
  u16x8 o;
  o[0]=f2bf(v0[0]); o[1]=f2bf(v0[1]); o[2]=f2bf(v0[2]); o[3]=f2bf(v0[3]);
  o[4]=f2bf(v1[0]); o[5]=f2bf(v1[1]); o[6]=f2bf(v1[2]); o[7]=f2bf(v1[3]);
  *(u16x8*)(xb + i) = o;
}

// ------- batched transpose + convert: [E][R][C] f32 -> [E][C][R] bf16 --------
__global__ __launch_bounds__(256) void transpose_kernel(
    const float* __restrict__ w, unsigned short* __restrict__ wt, int R, int C)
{
  __shared__ float tile[64][65];
  int tilesPerRow = C >> 6;
  int tilesPerMat = (R >> 6) * tilesPerRow;
  int b = blockIdx.x;
  int e = b / tilesPerMat;
  int rem = b - e * tilesPerMat;
  int tr = rem / tilesPerRow;
  int tc = rem - tr * tilesPerRow;
  int tid = threadIdx.x;
  size_t ibase = (size_t)e*R*C + ((size_t)tr*64)*C + (size_t)tc*64;
#pragma unroll
  for (int i = 0; i < 16; i++) {
    int idx = tid + i*256;
    int r = idx >> 6, c = idx & 63;
    tile[r][c] = w[ibase + (size_t)r*C + c];
  }
  __syncthreads();
  size_t obase = (size_t)e*R*C + ((size_t)tc*64)*R + (size_t)tr*64;
#pragma unroll
  for (int i = 0; i < 16; i++) {
    int idx = tid + i*256;
    int r = idx >> 6, c = idx & 63;
    wt[obase + (size_t)r*R + c] = f2bf(tile[c][r]);
  }
}

// ================= 256x256 8-phase grouped GEMM (T2+T3+T4+T5) =================
// A: gathered rows (gemm1: xb via perm; gemm2: H rows direct), [256 x 64] / K-tile
// B: weights K-contig ([N][K]), [256 x 64] / K-tile.  LDS 128KB: [buf][op][half].
// Swizzle: byte ^= (row&7)<<4, applied inverse on global src, forward on ds_read.

#define STAGE_A(H_, T_) do { if ((T_) < KT) { int bb_ = ((T_) & 1);          \
  char* d_ = ldsb + ((bb_*2 + 0)*2 + (H_))*16384;                            \
  gload16(srcA[H_][0] + (size_t)(T_)*128, d_ + dst0);                        \
  gload16(srcA[H_][1] + (size_t)(T_)*128, d_ + dst1); } } while(0)

#define STAGE_B(H_, T_) do { if ((T_) < KT) { int bb_ = ((T_) & 1);          \
  char* d_ = ldsb + ((bb_*2 + 1)*2 + (H_))*16384;                            \
  gload16(srcB[H_][0] + (size_t)(T_)*128, d_ + dst0);                        \
  gload16(srcB[H_][1] + (size_t)(T_)*128, d_ + dst1); } } while(0)

#define PHASE(MH, NH, VM, ...)                                               \
  {                                                                          \
    bf16x8 afr[4][2]; bf16x8 bfr[2][2];                                      \
    const char* Ab = ldsb + (((buf*2 + 0)*2 + (MH))*16384);                  \
    const char* Bb = ldsb + (((buf*2 + 1)*2 + (NH))*16384);                  \
    _Pragma("unroll") for (int mi = 0; mi < 4; mi++) {                       \
      int row = rA + mi*16;                                                  \
      _Pragma("unroll") for (int ks = 0; ks < 2; ks++)                       \
        afr[mi][ks] = *(const bf16x8*)(Ab + row*128 + ((ks*64 + tb0) ^ ((row&7)<<4))); \
    }                                                                        \
    _Pragma("unroll") for (int ni = 0; ni < 2; ni++) {                       \
      int row = rB + ni*16;                                                  \
      _Pragma("unroll") for (int ks = 0; ks < 2; ks++)                       \
        bfr[ni][ks] = *(const bf16x8*)(Bb + row*128 + ((ks*64 + tb0) ^ ((row&7)<<4))); \
    }                                                                        \
    __VA_ARGS__;                                                             \
    __builtin_amdgcn_s_barrier();                                            \
    __builtin_amdgcn_s_setprio(1);                                           \
    _Pragma("unroll") for (int ks = 0; ks < 2; ks++)                         \
      _Pragma("unroll") for (int mi = 0; mi < 4; mi++)                       \
        _Pragma("unroll") for (int ni = 0; ni < 2; ni++)                     \
          acc[(MH)*4+mi][(NH)*2+ni] = __builtin_amdgcn_mfma_f32_16x16x32_bf16( \
              afr[mi][ks], bfr[ni][ks], acc[(MH)*4+mi][(NH)*2+ni], 0, 0, 0); \
    __builtin_amdgcn_s_setprio(0);                                           \
    __builtin_amdgcn_sched_barrier(0);                                       \
    asm volatile("s_waitcnt vmcnt(" VM ")" ::: "memory");                    \
    __builtin_amdgcn_s_barrier();                                            \
  }

template<int KDIM, int NDIM, bool GELU>
__global__ __launch_bounds__(512, 2) void gemm256(
    const unsigned short* __restrict__ Asrc,
    const unsigned short* __restrict__ Bsrc,
    const float* __restrict__ bias,
    const int* __restrict__ perm,
    const int* __restrict__ offsets,
    void* __restrict__ Cout)
{
  constexpr int KT = KDIM / 64;
  constexpr int NT = NDIM / 256;
  int b = blockIdx.x;
  int e = b / (MAXMT * NT);
  int rem = b - e * (MAXMT * NT);
  int rt = rem / NT;
  int nt = rem - rt * NT;
  int off = offsets[e];
  int n_e = offsets[e+1] - off;
  if (rt * 256 >= n_e) return;

  __shared__ __align__(16) unsigned short lds[2*2*2*8192];   // 128 KiB
  char* ldsb = (char*)lds;

  int tid = threadIdx.x;
  int lane = tid & 63;
  int wid = tid >> 6;
  int wr = wid >> 2;          // 0..1  (M strips)
  int wc = wid & 3;           // 0..3  (N strips)
  int rA  = wr*64 + (lane & 15);
  int rB  = wc*32 + (lane & 15);
  int tb0 = (lane >> 4) * 16;

  // per-thread stage pointers (inverse-swizzled global source, linear LDS dest)
  const char* srcA[2][2];
  const char* srcB[2][2];
#pragma unroll
  for (int h = 0; h < 2; h++) {
#pragma unroll
    for (int i = 0; i < 2; i++) {
      int slot = tid + i*512;
      int r = slot >> 3;
      int kc = (slot & 7) ^ (r & 7);
      int g = off + rt*256 + h*128 + r;
      if (g > NASG-1) g = NASG-1;
      size_t arow = GELU ? (size_t)perm[g] : (size_t)g;
      srcA[h][i] = (const char*)Asrc + (arow * KDIM + (size_t)kc*8) * 2;
      int col = nt*256 + h*128 + r;
      srcB[h][i] = (const char*)Bsrc + (((size_t)e*NDIM + col) * KDIM + (size_t)kc*8) * 2;
    }
  }
  int dst0 = tid*16;
  int dst1 = tid*16 + 8192;

  f32x4 acc[8][4];
#pragma unroll
  for (int m = 0; m < 8; m++)
#pragma unroll
    for (int n = 0; n < 4; n++) acc[m][n] = (f32x4){0.f,0.f,0.f,0.f};

  // prologue: kt0 all 4 halves + kt1 Ah0/Bh0 (12 loads); force kt0 complete
  STAGE_A(0, 0);
  STAGE_B(0, 0);
  STAGE_B(1, 0);
  STAGE_A(1, 0);
  STAGE_A(0, 1);
  STAGE_B(0, 1);
  asm volatile("s_waitcnt vmcnt(4)" ::: "memory");
  __builtin_amdgcn_s_barrier();

#pragma unroll 1
  for (int kt = 0; kt < KT-2; kt++) {
    int buf = kt & 1;
    PHASE(0,0, "8", STAGE_B(1, kt+1))
    PHASE(0,1, "8", STAGE_A(1, kt+1))
    PHASE(1,0, "8", STAGE_A(0, kt+2))
    PHASE(1,1, "8", STAGE_B(0, kt+2))
  }
#pragma unroll 1
  for (int kt = KT-2; kt < KT; kt++) {   // drain tail: full waits
    int buf = kt & 1;
    PHASE(0,0, "0", STAGE_B(1, kt+1))
    PHASE(0,1, "0", STAGE_A(1, kt+1))
    PHASE(1,0, "0", STAGE_A(0, kt+2))
    PHASE(1,1, "0", STAGE_B(0, kt+2))
  }

  // epilogue
  int rq = (lane >> 4) * 4;
  int lc = lane & 15;
  if (GELU) {
    unsigned short* H = (unsigned short*)Cout;
#pragma unroll
    for (int mh = 0; mh < 2; mh++)
#pragma unroll
      for (int mi = 0; mi < 4; mi++)
#pragma unroll
        for (int j = 0; j < 4; j++) {
          int sl = rt*256 + mh*128 + wr*64 + mi*16 + rq + j;
          if (sl < n_e) {
            size_t hrow = (size_t)(off + sl) * NDIM;
#pragma unroll
            for (int nh = 0; nh < 2; nh++)
#pragma unroll
              for (int ni = 0; ni < 2; ni++) {
                int col = nt*256 + nh*128 + wc*32 + ni*16 + lc;
                float v = acc[mh*4+mi][nh*2+ni][j] + bias[e*NDIM + col];
                float g = 0.5f * v * (1.0f + erff(v * 0.70710678118654752f));
                H[hrow + col] = f2bf(g);
              }
          }
        }
  } else {
    float* Y = (float*)Cout;
#pragma unroll
    for (int mh = 0; mh < 2; mh++)
#pragma unroll
      for (int mi = 0; mi < 4; mi++)
#pragma unroll
        for (int j = 0; j < 4; j++) {
          int sl = rt*256 + mh*128 + wr*64 + mi*16 + rq + j;
          if (sl < n_e) {
            size_t yrow = (size_t)(off + sl) * NDIM;
#pragma unroll
            for (int nh = 0; nh < 2; nh++)
#pragma unroll
              for (int ni = 0; ni < 2; ni++) {
                int col = nt*256 + nh*128 + wc*32 + ni*16 + lc;
                Y[yrow + col] = acc[mh*4+mi][nh*2+ni][j];
              }
          }
        }
  }
}

// ---------- combine: out[t] = sum_k w_k * (Y[slot_k] + b2[e_k]) ----------
__global__ __launch_bounds__(256) void combine_kernel(
    const float* __restrict__ Y, const float* __restrict__ b2,
    const int* __restrict__ topi, const float* __restrict__ topw,
    const int* __restrict__ islot, float* __restrict__ out)
{
  int t = blockIdx.x;
  int s0 = islot[t*2], s1 = islot[t*2+1];
  int e0 = topi[t*2],  e1 = topi[t*2+1];
  float w0 = topw[t*2], w1 = topw[t*2+1];
  int d = threadIdx.x * 4;
  f4v y0 = *(const f4v*)(Y + (size_t)s0*DDIM + d);
  f4v y1 = *(const f4v*)(Y + (size_t)s1*DDIM + d);
  f4v c0 = *(const f4v*)(b2 + (size_t)e0*DDIM + d);
  f4v c1 = *(const f4v*)(b2 + (size_t)e1*DDIM + d);
  f4v o = w0*(y0+c0) + w1*(y1+c1);
  *(f4v*)(out + (size_t)t*DDIM + d) = o;
}

extern "C" void kernel_launch(void* const* d_in, const int* in_sizes, int n_in,
                              void* d_out, int out_size, void* d_ws, size_t ws_size,
                              hipStream_t stream) {
  const float* x  = (const float*)d_in[0];
  const float* w1 = (const float*)d_in[1];
  const float* b1 = (const float*)d_in[2];
  const float* w2 = (const float*)d_in[3];
  const float* b2 = (const float*)d_in[4];
  const float* rw = (const float*)d_in[5];
  const float* rb = (const float*)d_in[6];
  float* out = (float*)d_out;

  char* p = (char*)d_ws;
  size_t o = 0;
  auto take = [&](size_t bytes) -> void* {
    void* r = p + o;
    o = (o + bytes + 255) & ~(size_t)255;
    return r;
  };
  int*            counts  = (int*)take(NEXP * 4);
  int*            offsets = (int*)take((NEXP + 1) * 4);
  int*            topi    = (int*)take((size_t)NASG * 4);
  float*          topw    = (float*)take((size_t)NASG * 4);
  int*            perm    = (int*)take((size_t)NASG * 4);
  int*            islot   = (int*)take((size_t)NASG * 4);
  unsigned short* w1t     = (unsigned short*)take((size_t)NEXP * FDIM * DDIM * 2);
  unsigned short* xb      = (unsigned short*)take((size_t)TTOK * DDIM * 2);
  unsigned short* w2t     = (unsigned short*)take((size_t)NEXP * DDIM * FDIM * 2);
  unsigned short* H       = (unsigned short*)take((size_t)NASG * FDIM * 2);
  // Y aliases w1t (dead after gemm1): NASG*DDIM*4 = 64 MiB = exactly w1t's size
  float*          Y       = (float*)w1t;

  if (o > ws_size) {   // workspace insufficient: fail visibly (zeros)
    hipMemsetAsync(d_out, 0, (size_t)out_size * 4, stream);
    return;
  }

  hipMemsetAsync(counts, 0, NEXP * 4, stream);

  router_kernel<<<TTOK/4, 256, 0, stream>>>(x, rw, rb, topi, topw, counts);
  scan_kernel<<<1, 64, 0, stream>>>(counts, offsets);
  permbuild_kernel<<<1, 256, 0, stream>>>(topi, offsets, perm, islot);
  cvt_x_kernel<<<(TTOK*DDIM/8)/256, 256, 0, stream>>>(x, xb);
  transpose_kernel<<<NEXP*(DDIM/64)*(FDIM/64), 256, 0, stream>>>(w1, w1t, DDIM, FDIM);
  transpose_kernel<<<NEXP*(FDIM/64)*(DDIM/64), 256, 0, stream>>>(w2, w2t, FDIM, DDIM);
  gemm256<DDIM, FDIM, true ><<<NEXP*MAXMT*(FDIM/256), 512, 0, stream>>>(xb, w1t, b1, perm, offsets, (void*)H);
  gemm256<FDIM, DDIM, false><<<NEXP*MAXMT*(DDIM/256), 512, 0, stream>>>(H, w2t, nullptr, nullptr, offsets, (void*)Y);
  combine_kernel<<<TTOK, 256, 0, stream>>>(Y, b2, topi, topw, islot, out);
}

// Round 3
// 794.111 us; speedup vs baseline: 1.3598x; 1.0586x over previous
//
#include <hip/hip_runtime.h>
#include <stdint.h>
#include <math.h>

#define TTOK 8192
#define DDIM 1024
#define FDIM 4096
#define NEXP 8
#define NASG (TTOK*2)
#define MAXMT 32   // max 256-row tiles per expert (worst case: all tokens on one expert)

typedef __attribute__((ext_vector_type(8))) short bf16x8;
typedef __attribute__((ext_vector_type(4))) float f32x4;
typedef __attribute__((ext_vector_type(4))) float f4v;
typedef __attribute__((ext_vector_type(8))) unsigned short u16x8;

__device__ __forceinline__ unsigned short f2bf(float f) {
  union { float f; unsigned int u; } v; v.f = f;
  unsigned int u = v.u;
  u += 0x7fffu + ((u >> 16) & 1u);   // round-to-nearest-even
  return (unsigned short)(u >> 16);
}

__device__ __forceinline__ void gload16(const void* g, void* l) {
  __builtin_amdgcn_global_load_lds(
    (__attribute__((address_space(1))) unsigned int*)(uintptr_t)g,
    (__attribute__((address_space(3))) unsigned int*)(uintptr_t)l,
    16, 0, 0);
}

// ---------------- router: one wave per token, fp64 accumulate ----------------
__global__ __launch_bounds__(256) void router_kernel(
    const float* __restrict__ x, const float* __restrict__ rw,
    const float* __restrict__ rb, int* __restrict__ topi,
    float* __restrict__ topw, int* __restrict__ counts)
{
  int wave = threadIdx.x >> 6;
  int lane = threadIdx.x & 63;
  int t = blockIdx.x * 4 + wave;
  if (t >= TTOK) return;
  double acc[8];
#pragma unroll
  for (int e = 0; e < 8; e++) acc[e] = 0.0;
  const float* xr = x + (size_t)t * DDIM;
  for (int d = lane; d < DDIM; d += 64) {
    double xv = (double)xr[d];
    const float* rwr = rw + (size_t)d * 8;
#pragma unroll
    for (int e = 0; e < 8; e++) acc[e] += xv * (double)rwr[e];
  }
#pragma unroll
  for (int e = 0; e < 8; e++) {
    for (int off = 32; off >= 1; off >>= 1)
      acc[e] += __shfl_xor(acc[e], off);
  }
  if (lane == 0) {
    float lg[8];
#pragma unroll
    for (int e = 0; e < 8; e++) lg[e] = (float)acc[e] + rb[e];
    int i0 = 0;
    for (int e = 1; e < 8; e++) if (lg[e] > lg[i0]) i0 = e;   // ties -> lowest idx
    int i1 = -1;
    for (int e = 0; e < 8; e++) {
      if (e == i0) continue;
      if (i1 < 0 || lg[e] > lg[i1]) i1 = e;
    }
    double z = exp((double)lg[i1] - (double)lg[i0]);
    float w0 = (float)(1.0 / (1.0 + z));
    topi[t*2]   = i0;  topi[t*2+1] = i1;
    topw[t*2]   = w0;  topw[t*2+1] = 1.0f - w0;
    atomicAdd(&counts[i0], 1);
    atomicAdd(&counts[i1], 1);
  }
}

__global__ void scan_kernel(const int* __restrict__ counts, int* __restrict__ offsets) {
  if (threadIdx.x == 0) {
    int s = 0;
    for (int e = 0; e < 8; e++) { offsets[e] = s; s += counts[e]; }
    offsets[8] = s;
  }
}

// ------------- deterministic stable counting sort of assignments -------------
__global__ __launch_bounds__(256) void permbuild_kernel(
    const int* __restrict__ topi, const int* __restrict__ offsets,
    int* __restrict__ perm, int* __restrict__ islot)
{
  __shared__ int hist[256 * 8];
  int tid = threadIdx.x;
  int cnt[8];
#pragma unroll
  for (int e = 0; e < 8; e++) cnt[e] = 0;
  int base = tid * 64;
  for (int i = 0; i < 64; i++) cnt[topi[base + i]]++;
#pragma unroll
  for (int e = 0; e < 8; e++) hist[tid*8 + e] = cnt[e];
  __syncthreads();
  if (tid < 8) {
    int s = 0;
    for (int th = 0; th < 256; th++) { int v = hist[th*8 + tid]; hist[th*8 + tid] = s; s += v; }
  }
  __syncthreads();
  int pos[8];
#pragma unroll
  for (int e = 0; e < 8; e++) pos[e] = offsets[e] + hist[tid*8 + e];
  for (int i = 0; i < 64; i++) {
    int a = base + i;
    int e = topi[a];
    int p = pos[e]++;
    perm[p] = a >> 1;
    islot[a] = p;
  }
}

// ---------------- x fp32 -> bf16 ----------------
__global__ __launch_bounds__(256) void cvt_x_kernel(
    const float* __restrict__ x, unsigned short* __restrict__ xb)
{
  size_t i = ((size_t)blockIdx.x * 256 + threadIdx.x) * 8;
  if (i >= (size_t)TTOK * DDIM) return;
  f4v v0 = *(const f4v*)(x + i);
  f4v v1 = *(const f4v*)(x + i + 4);
  u16x8 o;
  o[0]=f2bf(v0[0]); o[1]=f2bf(v0[1]); o[2]=f2bf(v0[2]); o[3]=f2bf(v0[3]);
  o[4]=f2bf(v1[0]); o[5]=f2bf(v1[1]); o[6]=f2bf(v1[2]); o[7]=f2bf(v1[3]);
  *(u16x8*)(xb + i) = o;
}

// ------- batched transpose + convert: [E][R][C] f32 -> [E][C][R] bf16 --------
__global__ __launch_bounds__(256) void transpose_kernel(
    const float* __restrict__ w, unsigned short* __restrict__ wt, int R, int C)
{
  __shared__ float tile[64][65];
  int tilesPerRow = C >> 6;
  int tilesPerMat = (R >> 6) * tilesPerRow;
  int b = blockIdx.x;
  int e = b / tilesPerMat;
  int rem = b - e * tilesPerMat;
  int tr = rem / tilesPerRow;
  int tc = rem - tr * tilesPerRow;
  int tid = threadIdx.x;
  size_t ibase = (size_t)e*R*C + ((size_t)tr*64)*C + (size_t)tc*64;
#pragma unroll
  for (int i = 0; i < 16; i++) {
    int idx = tid + i*256;
    int r = idx >> 6, c = idx & 63;
    tile[r][c] = w[ibase + (size_t)r*C + c];
  }
  __syncthreads();
  size_t obase = (size_t)e*R*C + ((size_t)tc*64)*R + (size_t)tr*64;
#pragma unroll
  for (int i = 0; i < 16; i++) {
    int idx = tid + i*256;
    int r = idx >> 6, c = idx & 63;
    wt[obase + (size_t)r*R + c] = f2bf(tile[c][r]);
  }
}

// ================= 256x256 grouped GEMM, min-LDS-read 4-phase =================
// A: gathered rows (gemm1: xb via perm; gemm2: H rows direct), [256 x 64] / K-tile
// B: weights K-contig ([N][K]), [256 x 64] / K-tile.  LDS 128KB: [buf][op][half].
// Swizzle: byte ^= (row&7)<<4, inverse on global src, forward on ds_read.
// Per K-tile: 24 ds_read_b128/thread (minimum), 1 counted vmcnt at P4.

#define STAGE_A(H_, T_) do { if ((T_) < KT) { int bb_ = ((T_) & 1);          \
  char* d_ = ldsb + ((bb_*2 + 0)*2 + (H_))*16384;                            \
  gload16(srcA[H_][0] + (size_t)(T_)*128, d_ + dst0);                        \
  gload16(srcA[H_][1] + (size_t)(T_)*128, d_ + dst1); } } while(0)

#define STAGE_B(H_, T_) do { if ((T_) < KT) { int bb_ = ((T_) & 1);          \
  char* d_ = ldsb + ((bb_*2 + 1)*2 + (H_))*16384;                            \
  gload16(srcB[H_][0] + (size_t)(T_)*128, d_ + dst0);                        \
  gload16(srcB[H_][1] + (size_t)(T_)*128, d_ + dst1); } } while(0)

#define READ_A(DST, MH)                                                      \
  { const char* Ab = ldsb + (((buf)*2 + 0)*2 + (MH))*16384;                  \
    _Pragma("unroll") for (int mi = 0; mi < 4; mi++) {                       \
      int row = rA + mi*16;                                                  \
      _Pragma("unroll") for (int ks = 0; ks < 2; ks++)                       \
        DST[mi][ks] = *(const bf16x8*)(Ab + row*128 + ((ks*64 + tb0) ^ ((row&7)<<4))); } }

#define READ_B(DST, NH)                                                      \
  { const char* Bb = ldsb + (((buf)*2 + 1)*2 + (NH))*16384;                  \
    _Pragma("unroll") for (int ni = 0; ni < 2; ni++) {                       \
      int row = rB + ni*16;                                                  \
      _Pragma("unroll") for (int ks = 0; ks < 2; ks++)                       \
        DST[ni][ks] = *(const bf16x8*)(Bb + row*128 + ((ks*64 + tb0) ^ ((row&7)<<4))); } }

#define MFMA_Q(MH, NH, A_, B_)                                               \
    __builtin_amdgcn_s_setprio(1);                                           \
    _Pragma("unroll") for (int ks = 0; ks < 2; ks++)                         \
      _Pragma("unroll") for (int mi = 0; mi < 4; mi++)                       \
        _Pragma("unroll") for (int ni = 0; ni < 2; ni++)                     \
          acc[(MH)*4+mi][(NH)*2+ni] = __builtin_amdgcn_mfma_f32_16x16x32_bf16( \
              A_[mi][ks], B_[ni][ks], acc[(MH)*4+mi][(NH)*2+ni], 0, 0, 0);   \
    __builtin_amdgcn_s_setprio(0);

#define KTILE(KT_, VM)                                                       \
  { int buf = (KT_) & 1;                                                     \
    /* P1: Q(0,0) */                                                         \
    READ_A(afr, 0) READ_B(bfr0, 0)                                           \
    __builtin_amdgcn_sched_barrier(0);                                       \
    __builtin_amdgcn_s_barrier();                                            \
    MFMA_Q(0,0, afr, bfr0)                                                   \
    __builtin_amdgcn_s_barrier();                                            \
    /* P2: Q(0,1), A0 regs reused; A0/B0 regions of buf now dead -> stage kt+2 */ \
    READ_B(bfr1, 1)                                                          \
    STAGE_A(0, (KT_)+2); STAGE_B(0, (KT_)+2);                                \
    __builtin_amdgcn_sched_barrier(0);                                       \
    __builtin_amdgcn_s_barrier();                                            \
    MFMA_Q(0,1, afr, bfr1)                                                   \
    __builtin_amdgcn_s_barrier();                                            \
    /* P3: Q(1,1), B1 regs reused; B1 region dead -> stage */                \
    READ_A(afr, 1)                                                           \
    STAGE_B(1, (KT_)+2);                                                     \
    __builtin_amdgcn_sched_barrier(0);                                       \
    __builtin_amdgcn_s_barrier();                                            \
    MFMA_Q(1,1, afr, bfr1)                                                   \
    __builtin_amdgcn_s_barrier();                                            \
    /* P4: Q(1,0), all regs; A1 region dead -> stage; single counted vmcnt */\
    STAGE_A(1, (KT_)+2);                                                     \
    __builtin_amdgcn_sched_barrier(0);                                       \
    __builtin_amdgcn_s_barrier();                                            \
    MFMA_Q(1,0, afr, bfr0)                                                   \
    asm volatile("s_waitcnt vmcnt(" VM ")" ::: "memory");                    \
    __builtin_amdgcn_s_barrier();                                            \
  }

template<int KDIM, int NDIM, bool GELU>
__global__ __launch_bounds__(512, 2) void gemm256(
    const unsigned short* __restrict__ Asrc,
    const unsigned short* __restrict__ Bsrc,
    const float* __restrict__ bias,
    const int* __restrict__ perm,
    const int* __restrict__ offsets,
    void* __restrict__ Cout)
{
  constexpr int KT = KDIM / 64;
  constexpr int NT = NDIM / 256;
  int b = blockIdx.x;
  int e = b / (MAXMT * NT);
  int rem = b - e * (MAXMT * NT);
  int rt = rem / NT;
  int nt = rem - rt * NT;
  int off = offsets[e];
  int n_e = offsets[e+1] - off;
  if (rt * 256 >= n_e) return;

  __shared__ __align__(16) unsigned short lds[2*2*2*8192];   // 128 KiB
  char* ldsb = (char*)lds;

  int tid = threadIdx.x;
  int lane = tid & 63;
  int wid = tid >> 6;
  int wr = wid >> 2;          // 0..1  (M strips)
  int wc = wid & 3;           // 0..3  (N strips)
  int rA  = wr*64 + (lane & 15);
  int rB  = wc*32 + (lane & 15);
  int tb0 = (lane >> 4) * 16;

  // per-thread stage pointers (inverse-swizzled global source, linear LDS dest)
  const char* srcA[2][2];
  const char* srcB[2][2];
#pragma unroll
  for (int h = 0; h < 2; h++) {
#pragma unroll
    for (int i = 0; i < 2; i++) {
      int slot = tid + i*512;
      int r = slot >> 3;
      int kc = (slot & 7) ^ (r & 7);
      int g = off + rt*256 + h*128 + r;
      if (g > NASG-1) g = NASG-1;
      size_t arow = GELU ? (size_t)perm[g] : (size_t)g;
      srcA[h][i] = (const char*)Asrc + (arow * KDIM + (size_t)kc*8) * 2;
      int col = nt*256 + h*128 + r;
      srcB[h][i] = (const char*)Bsrc + (((size_t)e*NDIM + col) * KDIM + (size_t)kc*8) * 2;
    }
  }
  int dst0 = tid*16;
  int dst1 = tid*16 + 8192;

  f32x4 acc[8][4];
#pragma unroll
  for (int m = 0; m < 8; m++)
#pragma unroll
    for (int n = 0; n < 4; n++) acc[m][n] = (f32x4){0.f,0.f,0.f,0.f};

  bf16x8 afr[4][2];     // current A-half fragments
  bf16x8 bfr0[2][2];    // B-half 0 (live P1 -> P4)
  bf16x8 bfr1[2][2];    // B-half 1 (live P2 -> P3)

  // prologue: fully stage kt0 and kt1 (16 loads), retire kt0's 8
  STAGE_A(0, 0); STAGE_B(0, 0); STAGE_B(1, 0); STAGE_A(1, 0);
  STAGE_A(0, 1); STAGE_B(0, 1); STAGE_B(1, 1); STAGE_A(1, 1);
  asm volatile("s_waitcnt vmcnt(8)" ::: "memory");
  __builtin_amdgcn_s_barrier();

#pragma unroll 1
  for (int kt = 0; kt < KT-2; kt++) KTILE(kt, "8")
#pragma unroll 1
  for (int kt = KT-2; kt < KT; kt++) KTILE(kt, "0")   // drain tail

  // epilogue
  int rq = (lane >> 4) * 4;
  int lc = lane & 15;
  if (GELU) {
    unsigned short* H = (unsigned short*)Cout;
#pragma unroll
    for (int mh = 0; mh < 2; mh++)
#pragma unroll
      for (int mi = 0; mi < 4; mi++)
#pragma unroll
        for (int j = 0; j < 4; j++) {
          int sl = rt*256 + mh*128 + wr*64 + mi*16 + rq + j;
          if (sl < n_e) {
            size_t hrow = (size_t)(off + sl) * NDIM;
#pragma unroll
            for (int nh = 0; nh < 2; nh++)
#pragma unroll
              for (int ni = 0; ni < 2; ni++) {
                int col = nt*256 + nh*128 + wc*32 + ni*16 + lc;
                float v = acc[mh*4+mi][nh*2+ni][j] + bias[e*NDIM + col];
                float g = 0.5f * v * (1.0f + erff(v * 0.70710678118654752f));
                H[hrow + col] = f2bf(g);
              }
          }
        }
  } else {
    float* Y = (float*)Cout;
#pragma unroll
    for (int mh = 0; mh < 2; mh++)
#pragma unroll
      for (int mi = 0; mi < 4; mi++)
#pragma unroll
        for (int j = 0; j < 4; j++) {
          int sl = rt*256 + mh*128 + wr*64 + mi*16 + rq + j;
          if (sl < n_e) {
            size_t yrow = (size_t)(off + sl) * NDIM;
#pragma unroll
            for (int nh = 0; nh < 2; nh++)
#pragma unroll
              for (int ni = 0; ni < 2; ni++) {
                int col = nt*256 + nh*128 + wc*32 + ni*16 + lc;
                Y[yrow + col] = acc[mh*4+mi][nh*2+ni][j];
              }
          }
        }
  }
}

// ---------- combine: out[t] = sum_k w_k * (Y[slot_k] + b2[e_k]) ----------
__global__ __launch_bounds__(256) void combine_kernel(
    const float* __restrict__ Y, const float* __restrict__ b2,
    const int* __restrict__ topi, const float* __restrict__ topw,
    const int* __restrict__ islot, float* __restrict__ out)
{
  int t = blockIdx.x;
  int s0 = islot[t*2], s1 = islot[t*2+1];
  int e0 = topi[t*2],  e1 = topi[t*2+1];
  float w0 = topw[t*2], w1 = topw[t*2+1];
  int d = threadIdx.x * 4;
  f4v y0 = *(const f4v*)(Y + (size_t)s0*DDIM + d);
  f4v y1 = *(const f4v*)(Y + (size_t)s1*DDIM + d);
  f4v c0 = *(const f4v*)(b2 + (size_t)e0*DDIM + d);
  f4v c1 = *(const f4v*)(b2 + (size_t)e1*DDIM + d);
  f4v o = w0*(y0+c0) + w1*(y1+c1);
  *(f4v*)(out + (size_t)t*DDIM + d) = o;
}

extern "C" void kernel_launch(void* const* d_in, const int* in_sizes, int n_in,
                              void* d_out, int out_size, void* d_ws, size_t ws_size,
                              hipStream_t stream) {
  const float* x  = (const float*)d_in[0];
  const float* w1 = (const float*)d_in[1];
  const float* b1 = (const float*)d_in[2];
  const float* w2 = (const float*)d_in[3];
  const float* b2 = (const float*)d_in[4];
  const float* rw = (const float*)d_in[5];
  const float* rb = (const float*)d_in[6];
  float* out = (float*)d_out;

  char* p = (char*)d_ws;
  size_t o = 0;
  auto take = [&](size_t bytes) -> void* {
    void* r = p + o;
    o = (o + bytes + 255) & ~(size_t)255;
    return r;
  };
  int*            counts  = (int*)take(NEXP * 4);
  int*            offsets = (int*)take((NEXP + 1) * 4);
  int*            topi    = (int*)take((size_t)NASG * 4);
  float*          topw    = (float*)take((size_t)NASG * 4);
  int*            perm    = (int*)take((size_t)NASG * 4);
  int*            islot   = (int*)take((size_t)NASG * 4);
  unsigned short* w1t     = (unsigned short*)take((size_t)NEXP * FDIM * DDIM * 2);
  unsigned short* xb      = (unsigned short*)take((size_t)TTOK * DDIM * 2);
  unsigned short* w2t     = (unsigned short*)take((size_t)NEXP * DDIM * FDIM * 2);
  unsigned short* H       = (unsigned short*)take((size_t)NASG * FDIM * 2);
  // Y aliases w1t (dead after gemm1): NASG*DDIM*4 = 64 MiB = exactly w1t's size
  float*          Y       = (float*)w1t;

  if (o > ws_size) {   // workspace insufficient: fail visibly (zeros)
    hipMemsetAsync(d_out, 0, (size_t)out_size * 4, stream);
    return;
  }

  hipMemsetAsync(counts, 0, NEXP * 4, stream);

  router_kernel<<<TTOK/4, 256, 0, stream>>>(x, rw, rb, topi, topw, counts);
  scan_kernel<<<1, 64, 0, stream>>>(counts, offsets);
  permbuild_kernel<<<1, 256, 0, stream>>>(topi, offsets, perm, islot);
  cvt_x_kernel<<<(TTOK*DDIM/8)/256, 256, 0, stream>>>(x, xb);
  transpose_kernel<<<NEXP*(DDIM/64)*(FDIM/64), 256, 0, stream>>>(w1, w1t, DDIM, FDIM);
  transpose_kernel<<<NEXP*(FDIM/64)*(DDIM/64), 256, 0, stream>>>(w2, w2t, FDIM, DDIM);
  gemm256<DDIM, FDIM, true ><<<NEXP*MAXMT*(FDIM/256), 512, 0, stream>>>(xb, w1t, b1, perm, offsets, (void*)H);
  gemm256<FDIM, DDIM, false><<<NEXP*MAXMT*(DDIM/256), 512, 0, stream>>>(H, w2t, nullptr, nullptr, offsets, (void*)Y);
  combine_kernel<<<TTOK, 256, 0, stream>>>(Y, b2, topi, topw, islot, out);
}

// Round 4
// 759.591 us; speedup vs baseline: 1.4216x; 1.0454x over previous
//
#include <hip/hip_runtime.h>
#include <stdint.h>
#include <math.h>

#define TTOK 8192
#define DDIM 1024
#define FDIM 4096
#define NEXP 8
#define NASG (TTOK*2)
#define MAXMT 32   // max 256-row tiles per expert (worst case: all tokens on one expert)

typedef __attribute__((ext_vector_type(8))) short bf16x8;
typedef __attribute__((ext_vector_type(4))) float f32x4;
typedef __attribute__((ext_vector_type(4))) float f4v;
typedef __attribute__((ext_vector_type(8))) unsigned short u16x8;

__device__ __forceinline__ unsigned short f2bf(float f) {
  union { float f; unsigned int u; } v; v.f = f;
  unsigned int u = v.u;
  u += 0x7fffu + ((u >> 16) & 1u);   // round-to-nearest-even
  return (unsigned short)(u >> 16);
}

__device__ __forceinline__ void gload16(const void* g, void* l) {
  __builtin_amdgcn_global_load_lds(
    (__attribute__((address_space(1))) unsigned int*)(uintptr_t)g,
    (__attribute__((address_space(3))) unsigned int*)(uintptr_t)l,
    16, 0, 0);
}

// ------ router: one wave per token, fp64 accumulate; also emits xb (bf16) ------
__global__ __launch_bounds__(256) void router_kernel(
    const float* __restrict__ x, const float* __restrict__ rw,
    const float* __restrict__ rb, int* __restrict__ topi,
    float* __restrict__ topw, int* __restrict__ counts,
    unsigned short* __restrict__ xb)
{
  int wave = threadIdx.x >> 6;
  int lane = threadIdx.x & 63;
  int t = blockIdx.x * 4 + wave;
  if (t >= TTOK) return;
  double acc[8];
#pragma unroll
  for (int e = 0; e < 8; e++) acc[e] = 0.0;
  const float* xr = x + (size_t)t * DDIM;
  unsigned short* xbr = xb + (size_t)t * DDIM;
  for (int d = lane; d < DDIM; d += 64) {
    float xf = xr[d];
    xbr[d] = f2bf(xf);
    double xv = (double)xf;
    const float* rwr = rw + (size_t)d * 8;
#pragma unroll
    for (int e = 0; e < 8; e++) acc[e] += xv * (double)rwr[e];
  }
#pragma unroll
  for (int e = 0; e < 8; e++) {
    for (int off = 32; off >= 1; off >>= 1)
      acc[e] += __shfl_xor(acc[e], off);
  }
  if (lane == 0) {
    float lg[8];
#pragma unroll
    for (int e = 0; e < 8; e++) lg[e] = (float)acc[e] + rb[e];
    int i0 = 0;
    for (int e = 1; e < 8; e++) if (lg[e] > lg[i0]) i0 = e;   // ties -> lowest idx
    int i1 = -1;
    for (int e = 0; e < 8; e++) {
      if (e == i0) continue;
      if (i1 < 0 || lg[e] > lg[i1]) i1 = e;
    }
    double z = exp((double)lg[i1] - (double)lg[i0]);
    float w0 = (float)(1.0 / (1.0 + z));
    topi[t*2]   = i0;  topi[t*2+1] = i1;
    topw[t*2]   = w0;  topw[t*2+1] = 1.0f - w0;
    atomicAdd(&counts[i0], 1);
    atomicAdd(&counts[i1], 1);
  }
}

// ------ deterministic stable counting sort (single block; includes scan) ------
__global__ __launch_bounds__(256) void permbuild_kernel(
    const int* __restrict__ topi, const int* __restrict__ counts,
    int* __restrict__ offsets, int* __restrict__ perm, int* __restrict__ islot)
{
  __shared__ int hist[256 * 8];
  __shared__ int offs[NEXP + 1];
  int tid = threadIdx.x;
  if (tid == 0) {
    int s = 0;
    for (int e = 0; e < 8; e++) { offs[e] = s; s += counts[e]; }
    offs[8] = s;
    for (int e = 0; e <= 8; e++) offsets[e] = offs[e];
  }
  int cnt[8];
#pragma unroll
  for (int e = 0; e < 8; e++) cnt[e] = 0;
  int base = tid * 64;
  for (int i = 0; i < 64; i++) cnt[topi[base + i]]++;
#pragma unroll
  for (int e = 0; e < 8; e++) hist[tid*8 + e] = cnt[e];
  __syncthreads();
  if (tid < 8) {
    int s = 0;
    for (int th = 0; th < 256; th++) { int v = hist[th*8 + tid]; hist[th*8 + tid] = s; s += v; }
  }
  __syncthreads();
  int pos[8];
#pragma unroll
  for (int e = 0; e < 8; e++) pos[e] = offs[e] + hist[tid*8 + e];
  for (int i = 0; i < 64; i++) {
    int a = base + i;
    int e = topi[a];
    int p = pos[e]++;
    perm[p] = a >> 1;
    islot[a] = p;
  }
}

// ------- batched transpose + convert: [E][R][C] f32 -> [E][C][R] bf16 --------
__global__ __launch_bounds__(256) void transpose_kernel(
    const float* __restrict__ w, unsigned short* __restrict__ wt, int R, int C)
{
  __shared__ float tile[64][65];
  int tilesPerRow = C >> 6;
  int tilesPerMat = (R >> 6) * tilesPerRow;
  int b = blockIdx.x;
  int e = b / tilesPerMat;
  int rem = b - e * tilesPerMat;
  int tr = rem / tilesPerRow;
  int tc = rem - tr * tilesPerRow;
  int tid = threadIdx.x;
  size_t ibase = (size_t)e*R*C + ((size_t)tr*64)*C + (size_t)tc*64;
#pragma unroll
  for (int i = 0; i < 16; i++) {
    int idx = tid + i*256;
    int r = idx >> 6, c = idx & 63;
    tile[r][c] = w[ibase + (size_t)r*C + c];
  }
  __syncthreads();
  size_t obase = (size_t)e*R*C + ((size_t)tc*64)*R + (size_t)tr*64;
#pragma unroll
  for (int i = 0; i < 16; i++) {
    int idx = tid + i*256;
    int r = idx >> 6, c = idx & 63;
    wt[obase + (size_t)r*R + c] = f2bf(tile[c][r]);
  }
}

// ========== 256x256 grouped GEMM, register read-ahead 4-phase pipeline =========
// Quadrant order Q00 -> Q01 -> Q10 -> Q11; each ds_read group is issued one
// full MFMA cluster before its consuming quadrant.  4 barriers / K-tile.
// Swizzle: byte ^= (row&7)<<4, inverse on global src, forward on ds_read.

#define STAGE_A(H_, T_) do { if ((T_) < KT) { int bb_ = ((T_) & 1);          \
  char* d_ = ldsb + ((bb_*2 + 0)*2 + (H_))*16384;                            \
  gload16(srcA[H_][0] + (size_t)(T_)*128, d_ + dst0);                        \
  gload16(srcA[H_][1] + (size_t)(T_)*128, d_ + dst1); } } while(0)

#define STAGE_B(H_, T_) do { if ((T_) < KT) { int bb_ = ((T_) & 1);          \
  char* d_ = ldsb + ((bb_*2 + 1)*2 + (H_))*16384;                            \
  gload16(srcB[H_][0] + (size_t)(T_)*128, d_ + dst0);                        \
  gload16(srcB[H_][1] + (size_t)(T_)*128, d_ + dst1); } } while(0)

#define READ_AF(DST, MH, BUF)                                                \
  { const char* Ab = ldsb + (((BUF)*2 + 0)*2 + (MH))*16384;                  \
    _Pragma("unroll") for (int mi = 0; mi < 4; mi++) {                       \
      int row = rA + mi*16;                                                  \
      _Pragma("unroll") for (int ks = 0; ks < 2; ks++)                       \
        DST[mi][ks] = *(const bf16x8*)(Ab + row*128 + ((ks*64 + tb0) ^ ((row&7)<<4))); } }

#define READ_BF(DST, NH, BUF)                                                \
  { const char* Bb = ldsb + (((BUF)*2 + 1)*2 + (NH))*16384;                  \
    _Pragma("unroll") for (int ni = 0; ni < 2; ni++) {                       \
      int row = rB + ni*16;                                                  \
      _Pragma("unroll") for (int ks = 0; ks < 2; ks++)                       \
        DST[ni][ks] = *(const bf16x8*)(Bb + row*128 + ((ks*64 + tb0) ^ ((row&7)<<4))); } }

#define MFMA_Q(MH, NH, A_, B_)                                               \
    __builtin_amdgcn_s_setprio(1);                                           \
    _Pragma("unroll") for (int ks = 0; ks < 2; ks++)                         \
      _Pragma("unroll") for (int mi = 0; mi < 4; mi++)                       \
        _Pragma("unroll") for (int ni = 0; ni < 2; ni++)                     \
          acc[(MH)*4+mi][(NH)*2+ni] = __builtin_amdgcn_mfma_f32_16x16x32_bf16( \
              A_[mi][ks], B_[ni][ks], acc[(MH)*4+mi][(NH)*2+ni], 0, 0, 0);   \
    __builtin_amdgcn_s_setprio(0);

#define KTILE(KT_, VM)                                                       \
  { int buf = (KT_) & 1; int bufn = ((KT_)+1) & 1;                           \
    /* P1: Q(0,0); read B1(kt) ahead for Q01 */                              \
    READ_BF(bfr1, 1, buf)                                                    \
    __builtin_amdgcn_sched_barrier(0);                                       \
    __builtin_amdgcn_s_barrier();                                            \
    MFMA_Q(0,0, afr0, bfr0)                                                  \
    /* P2: Q(0,1); read A1(kt) ahead for Q10; stage A0,B0(kt+2) */           \
    READ_AF(afr1, 1, buf)                                                    \
    STAGE_A(0, (KT_)+2); STAGE_B(0, (KT_)+2);                                \
    __builtin_amdgcn_sched_barrier(0);                                       \
    __builtin_amdgcn_s_barrier();                                            \
    MFMA_Q(0,1, afr0, bfr1)                                                  \
    /* P3: Q(1,0); stage B1(kt+2) */                                         \
    STAGE_B(1, (KT_)+2);                                                     \
    __builtin_amdgcn_sched_barrier(0);                                       \
    __builtin_amdgcn_s_barrier();                                            \
    MFMA_Q(1,0, afr1, bfr0)                                                  \
    /* P4: Q(1,1); stage A1(kt+2); vmcnt; barrier; read-ahead A0,B0(kt+1) */ \
    STAGE_A(1, (KT_)+2);                                                     \
    __builtin_amdgcn_sched_barrier(0);                                       \
    asm volatile("s_waitcnt vmcnt(" VM ")" ::: "memory");                    \
    __builtin_amdgcn_s_barrier();                                            \
    READ_AF(afr0, 0, bufn)                                                   \
    READ_BF(bfr0, 0, bufn)                                                   \
    __builtin_amdgcn_sched_barrier(0);                                       \
    MFMA_Q(1,1, afr1, bfr1)                                                  \
  }

template<int KDIM, int NDIM, bool GELU>
__global__ __launch_bounds__(512, 2) void gemm256(
    const unsigned short* __restrict__ Asrc,
    const unsigned short* __restrict__ Bsrc,
    const float* __restrict__ bias,
    const int* __restrict__ perm,
    const int* __restrict__ offsets,
    void* __restrict__ Cout)
{
  constexpr int KT = KDIM / 64;
  constexpr int NT = NDIM / 256;
  int b = blockIdx.x;
  int e = b / (MAXMT * NT);
  int rem = b - e * (MAXMT * NT);
  int rt = rem / NT;
  int nt = rem - rt * NT;
  int off = offsets[e];
  int n_e = offsets[e+1] - off;
  if (rt * 256 >= n_e) return;

  __shared__ __align__(16) unsigned short lds[2*2*2*8192];   // 128 KiB
  char* ldsb = (char*)lds;

  int tid = threadIdx.x;
  int lane = tid & 63;
  int wid = tid >> 6;
  int wr = wid >> 2;          // 0..1  (M strips)
  int wc = wid & 3;           // 0..3  (N strips)
  int rA  = wr*64 + (lane & 15);
  int rB  = wc*32 + (lane & 15);
  int tb0 = (lane >> 4) * 16;

  // per-thread stage pointers (inverse-swizzled global source, linear LDS dest)
  const char* srcA[2][2];
  const char* srcB[2][2];
#pragma unroll
  for (int h = 0; h < 2; h++) {
#pragma unroll
    for (int i = 0; i < 2; i++) {
      int slot = tid + i*512;
      int r = slot >> 3;
      int kc = (slot & 7) ^ (r & 7);
      int g = off + rt*256 + h*128 + r;
      if (g > NASG-1) g = NASG-1;
      size_t arow = GELU ? (size_t)perm[g] : (size_t)g;
      srcA[h][i] = (const char*)Asrc + (arow * KDIM + (size_t)kc*8) * 2;
      int col = nt*256 + h*128 + r;
      srcB[h][i] = (const char*)Bsrc + (((size_t)e*NDIM + col) * KDIM + (size_t)kc*8) * 2;
    }
  }
  int dst0 = tid*16;
  int dst1 = tid*16 + 8192;

  f32x4 acc[8][4];
#pragma unroll
  for (int m = 0; m < 8; m++)
#pragma unroll
    for (int n = 0; n < 4; n++) acc[m][n] = (f32x4){0.f,0.f,0.f,0.f};

  bf16x8 afr0[4][2], afr1[4][2];   // A half-0 / half-1 fragments
  bf16x8 bfr0[2][2], bfr1[2][2];   // B half-0 / half-1 fragments

  // prologue: fully stage kt0 and kt1 (16 loads), retire kt0's, pre-read A0,B0
  STAGE_A(0, 0); STAGE_B(0, 0); STAGE_B(1, 0); STAGE_A(1, 0);
  STAGE_A(0, 1); STAGE_B(0, 1); STAGE_B(1, 1); STAGE_A(1, 1);
  asm volatile("s_waitcnt vmcnt(8)" ::: "memory");
  __builtin_amdgcn_s_barrier();
  READ_AF(afr0, 0, 0)
  READ_BF(bfr0, 0, 0)
  __builtin_amdgcn_sched_barrier(0);

#pragma unroll 1
  for (int kt = 0; kt < KT-2; kt++) KTILE(kt, "8")
#pragma unroll 1
  for (int kt = KT-2; kt < KT; kt++) KTILE(kt, "0")   // drain tail

  // epilogue
  int rq = (lane >> 4) * 4;
  int lc = lane & 15;
  if (GELU) {
    unsigned short* H = (unsigned short*)Cout;
#pragma unroll
    for (int mh = 0; mh < 2; mh++)
#pragma unroll
      for (int mi = 0; mi < 4; mi++)
#pragma unroll
        for (int j = 0; j < 4; j++) {
          int sl = rt*256 + mh*128 + wr*64 + mi*16 + rq + j;
          if (sl < n_e) {
            size_t hrow = (size_t)(off + sl) * NDIM;
#pragma unroll
            for (int nh = 0; nh < 2; nh++)
#pragma unroll
              for (int ni = 0; ni < 2; ni++) {
                int col = nt*256 + nh*128 + wc*32 + ni*16 + lc;
                float v = acc[mh*4+mi][nh*2+ni][j] + bias[e*NDIM + col];
                float g = 0.5f * v * (1.0f + erff(v * 0.70710678118654752f));
                H[hrow + col] = f2bf(g);
              }
          }
        }
  } else {
    float* Y = (float*)Cout;
#pragma unroll
    for (int mh = 0; mh < 2; mh++)
#pragma unroll
      for (int mi = 0; mi < 4; mi++)
#pragma unroll
        for (int j = 0; j < 4; j++) {
          int sl = rt*256 + mh*128 + wr*64 + mi*16 + rq + j;
          if (sl < n_e) {
            size_t yrow = (size_t)(off + sl) * NDIM;
#pragma unroll
            for (int nh = 0; nh < 2; nh++)
#pragma unroll
              for (int ni = 0; ni < 2; ni++) {
                int col = nt*256 + nh*128 + wc*32 + ni*16 + lc;
                Y[yrow + col] = acc[mh*4+mi][nh*2+ni][j];
              }
          }
        }
  }
}

// ---------- combine: out[t] = sum_k w_k * (Y[slot_k] + b2[e_k]) ----------
__global__ __launch_bounds__(256) void combine_kernel(
    const float* __restrict__ Y, const float* __restrict__ b2,
    const int* __restrict__ topi, const float* __restrict__ topw,
    const int* __restrict__ islot, float* __restrict__ out)
{
  int t = blockIdx.x;
  int s0 = islot[t*2], s1 = islot[t*2+1];
  int e0 = topi[t*2],  e1 = topi[t*2+1];
  float w0 = topw[t*2], w1 = topw[t*2+1];
  int d = threadIdx.x * 4;
  f4v y0 = *(const f4v*)(Y + (size_t)s0*DDIM + d);
  f4v y1 = *(const f4v*)(Y + (size_t)s1*DDIM + d);
  f4v c0 = *(const f4v*)(b2 + (size_t)e0*DDIM + d);
  f4v c1 = *(const f4v*)(b2 + (size_t)e1*DDIM + d);
  f4v o = w0*(y0+c0) + w1*(y1+c1);
  *(f4v*)(out + (size_t)t*DDIM + d) = o;
}

extern "C" void kernel_launch(void* const* d_in, const int* in_sizes, int n_in,
                              void* d_out, int out_size, void* d_ws, size_t ws_size,
                              hipStream_t stream) {
  const float* x  = (const float*)d_in[0];
  const float* w1 = (const float*)d_in[1];
  const float* b1 = (const float*)d_in[2];
  const float* w2 = (const float*)d_in[3];
  const float* b2 = (const float*)d_in[4];
  const float* rw = (const float*)d_in[5];
  const float* rb = (const float*)d_in[6];
  float* out = (float*)d_out;

  char* p = (char*)d_ws;
  size_t o = 0;
  auto take = [&](size_t bytes) -> void* {
    void* r = p + o;
    o = (o + bytes + 255) & ~(size_t)255;
    return r;
  };
  int*            counts  = (int*)take(NEXP * 4);
  int*            offsets = (int*)take((NEXP + 1) * 4);
  int*            topi    = (int*)take((size_t)NASG * 4);
  float*          topw    = (float*)take((size_t)NASG * 4);
  int*            perm    = (int*)take((size_t)NASG * 4);
  int*            islot   = (int*)take((size_t)NASG * 4);
  unsigned short* w1t     = (unsigned short*)take((size_t)NEXP * FDIM * DDIM * 2);
  unsigned short* xb      = (unsigned short*)take((size_t)TTOK * DDIM * 2);
  unsigned short* w2t     = (unsigned short*)take((size_t)NEXP * DDIM * FDIM * 2);
  unsigned short* H       = (unsigned short*)take((size_t)NASG * FDIM * 2);
  // Y aliases w1t (dead after gemm1): NASG*DDIM*4 = 64 MiB = exactly w1t's size
  float*          Y       = (float*)w1t;

  if (o > ws_size) {   // workspace insufficient: fail visibly (zeros)
    hipMemsetAsync(d_out, 0, (size_t)out_size * 4, stream);
    return;
  }

  hipMemsetAsync(counts, 0, NEXP * 4, stream);

  router_kernel<<<TTOK/4, 256, 0, stream>>>(x, rw, rb, topi, topw, counts, xb);
  permbuild_kernel<<<1, 256, 0, stream>>>(topi, counts, offsets, perm, islot);
  transpose_kernel<<<NEXP*(DDIM/64)*(FDIM/64), 256, 0, stream>>>(w1, w1t, DDIM, FDIM);
  transpose_kernel<<<NEXP*(FDIM/64)*(DDIM/64), 256, 0, stream>>>(w2, w2t, FDIM, DDIM);
  gemm256<DDIM, FDIM, true ><<<NEXP*MAXMT*(FDIM/256), 512, 0, stream>>>(xb, w1t, b1, perm, offsets, (void*)H);
  gemm256<FDIM, DDIM, false><<<NEXP*MAXMT*(DDIM/256), 512, 0, stream>>>(H, w2t, nullptr, nullptr, offsets, (void*)Y);
  combine_kernel<<<TTOK, 256, 0, stream>>>(Y, b2, topi, topw, islot, out);
}